// Round 1
// baseline (1311.946 us; speedup 1.0000x reference)
//
#include <hip/hip_runtime.h>

// MMDNE fused kernel: wave-per-batch-element.
// rows: 0=s_fts, 1=t_fts, 2-3=s_h, 4-5=t_h, 6-15=s_neg, 16-25=t_neg
constexpr int Fdim = 128;
constexpr int Edim = 32;

__global__ __launch_bounds__(256) void mmdne_kernel(
    const float* __restrict__ s_fts,
    const float* __restrict__ t_fts,
    const float* __restrict__ s_h_fts,
    const float* __restrict__ t_h_fts,
    const float* __restrict__ s_neg,
    const float* __restrict__ t_neg,
    const float* __restrict__ ev_t,
    const float* __restrict__ s_h_times,
    const float* __restrict__ t_h_times,
    const float* __restrict__ s_mask,
    const float* __restrict__ t_mask,
    const float* __restrict__ Wg,
    const float* __restrict__ bft,
    const float* __restrict__ av,
    const float* __restrict__ dels,
    const float* __restrict__ delt,
    float* __restrict__ out,
    int nB, int total_waves)
{
    __shared__ float Wlds[Fdim * Edim];  // 16 KB, layout [f][e] -> banks 0..31 over e
    {
        const float4* src = (const float4*)Wg;
        float4* dst = (float4*)Wlds;
        #pragma unroll
        for (int i = 0; i < 4; i++) dst[threadIdx.x + 256 * i] = src[threadIdx.x + 256 * i];
    }
    __syncthreads();

    const int lane = threadIdx.x & 63;
    const int half = lane >> 5;   // half 0: f 0..63, s-side epilogue; half 1: f 64..127, t-side
    const int e    = lane & 31;

    const float a_cur = av[e];
    const float a_his = av[Edim + e];
    const float be    = bft[e];
    const float dl    = half ? delt[0] : dels[0];
    const int fbase   = half * 64;

    const int wave = (int)((blockIdx.x * blockDim.x + threadIdx.x) >> 6);

    for (int b = wave; b < nB; b += total_waves) {
        const float* ps  = s_fts   + (size_t)b * Fdim;
        const float* pt  = t_fts   + (size_t)b * Fdim;
        const float* psh = s_h_fts + (size_t)b * (2 * Fdim);
        const float* pth = t_h_fts + (size_t)b * (2 * Fdim);
        const float* psn = s_neg   + (size_t)b * (10 * Fdim);
        const float* ptn = t_neg   + (size_t)b * (10 * Fdim);

        float acc[26];
        #pragma unroll
        for (int r = 0; r < 26; r++) acc[r] = 0.f;

        // ---- Phase 1: embeddings. W chunk in registers, reused across all 26 rows.
        #pragma unroll 2
        for (int c = 0; c < 16; c++) {
            const int f = fbase + c * 4;
            const float w0 = Wlds[(f + 0) * Edim + e];
            const float w1 = Wlds[(f + 1) * Edim + e];
            const float w2 = Wlds[(f + 2) * Edim + e];
            const float w3 = Wlds[(f + 3) * Edim + e];
            auto step = [&](const float* p, float& a4) {
                float4 x = *(const float4*)(p + f);
                a4 = fmaf(x.x, w0, a4);
                a4 = fmaf(x.y, w1, a4);
                a4 = fmaf(x.z, w2, a4);
                a4 = fmaf(x.w, w3, a4);
            };
            step(ps, acc[0]);
            step(pt, acc[1]);
            step(psh, acc[2]);            step(psh + Fdim, acc[3]);
            step(pth, acc[4]);            step(pth + Fdim, acc[5]);
            #pragma unroll
            for (int n = 0; n < 10; n++) step(psn + n * Fdim, acc[6 + n]);
            #pragma unroll
            for (int n = 0; n < 10; n++) step(ptn + n * Fdim, acc[16 + n]);
        }

        // combine the two f-halves; every lane now holds all 26 embeddings for its e
        float y[26];
        #pragma unroll
        for (int r = 0; r < 26; r++) {
            y[r] = acc[r] + __shfl_xor(acc[r], 32) + be;
        }

        // ---- Phase 2: scores (half 0 computes s-side, half 1 t-side)
        float r0 = (half ? y[1] : y[0]) * a_cur;   // emb . a_cur
        float r1 = (half ? y[4] : y[2]) * a_his;   // h_emb[0] . a_his
        float r2 = (half ? y[5] : y[3]) * a_his;   // h_emb[1] . a_his
        #pragma unroll
        for (int m = 1; m <= 16; m <<= 1) {
            r0 += __shfl_xor(r0, m);
            r1 += __shfl_xor(r1, m);
            r2 += __shfl_xor(r2, m);
        }

        const float et = ev_t[b];
        const float* htp = half ? t_h_times : s_h_times;
        const float* mkp = half ? t_mask : s_mask;
        const float h0t = htp[2 * b], h1t = htp[2 * b + 1];
        const float m0  = mkp[2 * b], m1  = mkp[2 * b + 1];
        const float d0 = fabsf(et - h0t), d1 = fabsf(et - h1t);
        const float sc0 = r0 + r1, sc1 = r0 + r2;
        float sim0 = expf(-dl * d0) * sc0; sim0 = sim0 >= 0.f ? sim0 : 0.2f * sim0;
        float sim1 = expf(-dl * d1) * sc1; sim1 = sim1 >= 0.f ? sim1 : 0.2f * sim1;
        const float mx = fmaxf(sim0, sim1);
        const float p0 = expf(sim0 - mx), p1 = expf(sim1 - mx);
        const float inv = 1.f / (p0 + p1);
        const float w0_ = p0 * inv * expf(dl * d0) * m0;
        const float w1_ = p1 * inv * expf(dl * d1) * m1;

        // ---- p_lambda (s-side values; stored by lane 0 which is half 0)
        {
            float q0 = y[0] - y[1]; q0 *= q0;
            float q1 = y[2] - y[1]; q1 *= q1;
            float q2 = y[3] - y[1]; q2 *= q2;
            float comb = q0 + w0_ * q1 + w1_ * q2;   // fold before reducing (linearity)
            #pragma unroll
            for (int m = 1; m <= 16; m <<= 1) comb += __shfl_xor(comb, m);
            if (lane == 0) out[b] = -comb;
        }

        // ---- n_lambda_s (half 0) / n_lambda_t (half 1)
        float* onS = out + nB + (size_t)b * 10;
        float* onT = out + nB + (size_t)nB * 10 + (size_t)b * 10;
        const float Aa = half ? y[1] : y[0];
        const float Ha = half ? y[4] : y[2];
        const float Hb = half ? y[5] : y[3];
        #pragma unroll
        for (int n = 0; n < 10; n++) {
            const float cn = half ? y[6 + n] : y[16 + n];
            float u  = Aa - cn; u  *= u;
            float v0 = Ha - cn; v0 *= v0;
            float v1 = Hb - cn; v1 *= v1;
            float comb = u + w0_ * v0 + w1_ * v1;    // one butterfly per n
            #pragma unroll
            for (int m = 1; m <= 16; m <<= 1) comb += __shfl_xor(comb, m);
            if (lane == n)      onS[n] = -comb;
            if (lane == 32 + n) onT[n] = -comb;
        }
    }
}

extern "C" void kernel_launch(void* const* d_in, const int* in_sizes, int n_in,
                              void* d_out, int out_size, void* d_ws, size_t ws_size,
                              hipStream_t stream) {
    const float* s_fts     = (const float*)d_in[0];
    const float* t_fts     = (const float*)d_in[1];
    const float* s_h_fts   = (const float*)d_in[2];
    const float* t_h_fts   = (const float*)d_in[3];
    const float* s_neg     = (const float*)d_in[4];
    const float* t_neg     = (const float*)d_in[5];
    const float* ev_t      = (const float*)d_in[6];
    const float* s_h_times = (const float*)d_in[7];
    const float* t_h_times = (const float*)d_in[8];
    const float* s_mask    = (const float*)d_in[9];
    const float* t_mask    = (const float*)d_in[10];
    const float* Wg        = (const float*)d_in[11];
    const float* bft       = (const float*)d_in[12];
    const float* av        = (const float*)d_in[13];
    const float* dels      = (const float*)d_in[14];
    const float* delt      = (const float*)d_in[15];

    const int nB = in_sizes[6];          // event_time has B elements
    const int blocks = 1024;             // 4096 waves, ~12 b per wave
    const int total_waves = blocks * 4;

    mmdne_kernel<<<blocks, 256, 0, stream>>>(
        s_fts, t_fts, s_h_fts, t_h_fts, s_neg, t_neg, ev_t,
        s_h_times, t_h_times, s_mask, t_mask, Wg, bft, av, dels, delt,
        (float*)d_out, nB, total_waves);
}

// Round 2
// 624.371 us; speedup vs baseline: 2.1012x; 2.1012x over previous
//
#include <hip/hip_runtime.h>

typedef __attribute__((ext_vector_type(8))) short short8;
typedef __attribute__((ext_vector_type(4))) float f32x4;

constexpr int Fdim = 128;
constexpr int Edim = 32;
constexpr int NROW = 26;     // rows per b: s,t, s_h0,s_h1, t_h0,t_h1, s_neg0..9, t_neg0..9
constexpr int GB   = 16;     // b's per block (50000 = 16 * 3125 exactly)

static __device__ inline short f2bf(float x) {
    union { float f; unsigned u; } v; v.f = x;
    unsigned r = v.u + 0x7fffu + ((v.u >> 16) & 1u);   // RNE round to bf16
    return (short)(r >> 16);
}

static __device__ inline const float* row_ptr(int r, int b,
    const float* __restrict__ s1, const float* __restrict__ t1,
    const float* __restrict__ sh, const float* __restrict__ th,
    const float* __restrict__ sn, const float* __restrict__ tn)
{
    if (r == 0) return s1 + (size_t)b * Fdim;
    if (r == 1) return t1 + (size_t)b * Fdim;
    if (r < 6) {
        int i = r - 2;
        const float* base = (i < 2) ? sh : th;
        return base + (size_t)b * (2 * Fdim) + (size_t)(i & 1) * Fdim;
    }
    int i = r - 6;
    const float* base = (i < 10) ? sn : tn;
    if (i >= 10) i -= 10;
    return base + (size_t)b * (10 * Fdim) + (size_t)i * Fdim;
}

__global__ __launch_bounds__(256) void mmdne_kernel(
    const float* __restrict__ s_fts,
    const float* __restrict__ t_fts,
    const float* __restrict__ s_h_fts,
    const float* __restrict__ t_h_fts,
    const float* __restrict__ s_neg,
    const float* __restrict__ t_neg,
    const float* __restrict__ ev_t,
    const float* __restrict__ s_h_times,
    const float* __restrict__ t_h_times,
    const float* __restrict__ s_mask,
    const float* __restrict__ t_mask,
    const float* __restrict__ Wg,
    const float* __restrict__ bft,
    const float* __restrict__ av,
    const float* __restrict__ dels,
    const float* __restrict__ delt,
    float* __restrict__ out,
    int nB)
{
    // emb[type r][b_local][e]  (no bias added; bias cancels in sqnorm diffs)
    __shared__ float emb[NROW * GB * Edim];   // 53,248 B -> 3 blocks/CU

    const int tid  = threadIdx.x;
    const int lane = tid & 63;
    const int wid  = tid >> 6;
    const int b0   = blockIdx.x * GB;
    const int nlo  = lane & 15;   // MFMA: m (b_local) for A, n (e) for B, col for C
    const int kg   = lane >> 4;   // k-group 0..3

    // ---- Stage W (128x32 fp32, 16 KB) into LDS coalesced, reusing emb buffer
    {
        float* wl = emb;
        #pragma unroll
        for (int i = 0; i < 16; i++) wl[tid + 256 * i] = Wg[tid + 256 * i];
    }
    __syncthreads();

    // ---- Build persistent bf16 B-fragments: bf[nt][kk], B[k][n], n=lane&15, k=kg*8+j
    short8 bf[2][4];
    #pragma unroll
    for (int nt = 0; nt < 2; nt++)
        #pragma unroll
        for (int kk = 0; kk < 4; kk++)
            #pragma unroll
            for (int j = 0; j < 8; j++)
                bf[nt][kk][j] = f2bf(emb[(kk * 32 + kg * 8 + j) * Edim + nt * 16 + nlo]);

    // scalar score-bias: sum_e b[e]*(a_cur[e] + a_his[e])   (wave-uniform)
    float bias_cb = 0.f;
    for (int j = 0; j < Edim; j++) bias_cb += bft[j] * (av[j] + av[Edim + j]);

    __syncthreads();   // done reading W from LDS; emb buffer now reused for embeddings

    // ---- Phase 1: MFMA embeddings. Tile = 16 b's x one row-type, K=128, N=32.
    for (int r = wid; r < NROW; r += 4) {
        const float* rp = row_ptr(r, b0 + nlo, s_fts, t_fts, s_h_fts, t_h_fts, s_neg, t_neg);
        f32x4 xa[8];
        #pragma unroll
        for (int kk = 0; kk < 4; kk++) {
            const float* p = rp + kk * 32 + kg * 8;
            xa[2 * kk]     = *(const f32x4*)p;
            xa[2 * kk + 1] = *(const f32x4*)(p + 4);
        }
        f32x4 acc0 = {0.f, 0.f, 0.f, 0.f};
        f32x4 acc1 = {0.f, 0.f, 0.f, 0.f};
        #pragma unroll
        for (int kk = 0; kk < 4; kk++) {
            short8 af;
            #pragma unroll
            for (int j = 0; j < 4; j++) af[j]     = f2bf(xa[2 * kk][j]);
            #pragma unroll
            for (int j = 0; j < 4; j++) af[4 + j] = f2bf(xa[2 * kk + 1][j]);
            acc0 = __builtin_amdgcn_mfma_f32_16x16x32_bf16(af, bf[0][kk], acc0, 0, 0, 0);
            acc1 = __builtin_amdgcn_mfma_f32_16x16x32_bf16(af, bf[1][kk], acc1, 0, 0, 0);
        }
        // C layout: col = lane&15 (e), row = kg*4 + reg (b_local)
        #pragma unroll
        for (int reg = 0; reg < 4; reg++) {
            const int bl = kg * 4 + reg;
            emb[r * (GB * Edim) + bl * Edim + nlo]      = acc0[reg];
            emb[r * (GB * Edim) + bl * Edim + 16 + nlo] = acc1[reg];
        }
    }
    __syncthreads();

    // ---- Phase 2: epilogue (round-1 proven code; y from LDS, bias folded into scores)
    const int e    = lane & 31;
    const int half = lane >> 5;    // 0: s-side, 1: t-side
    const float a_cur = av[e];
    const float a_his = av[Edim + e];
    const float dl    = half ? delt[0] : dels[0];

    #pragma unroll
    for (int i = 0; i < 4; i++) {
        const int bl = wid * 4 + i;
        const int b  = b0 + bl;

        float y[26];
        #pragma unroll
        for (int r = 0; r < 26; r++) y[r] = emb[r * (GB * Edim) + bl * Edim + e];

        // scores (half 0: s-side, half 1: t-side)
        float r0 = (half ? y[1] : y[0]) * a_cur;
        float r1 = (half ? y[4] : y[2]) * a_his;
        float r2 = (half ? y[5] : y[3]) * a_his;
        #pragma unroll
        for (int m = 1; m <= 16; m <<= 1) {
            r0 += __shfl_xor(r0, m);
            r1 += __shfl_xor(r1, m);
            r2 += __shfl_xor(r2, m);
        }

        const float et = ev_t[b];
        const float* htp = half ? t_h_times : s_h_times;
        const float* mkp = half ? t_mask : s_mask;
        const float h0t = htp[2 * b], h1t = htp[2 * b + 1];
        const float m0  = mkp[2 * b], m1  = mkp[2 * b + 1];
        const float d0 = fabsf(et - h0t), d1 = fabsf(et - h1t);
        const float sc0 = r0 + r1 + bias_cb, sc1 = r0 + r2 + bias_cb;
        float sim0 = expf(-dl * d0) * sc0; sim0 = sim0 >= 0.f ? sim0 : 0.2f * sim0;
        float sim1 = expf(-dl * d1) * sc1; sim1 = sim1 >= 0.f ? sim1 : 0.2f * sim1;
        const float mx = fmaxf(sim0, sim1);
        const float p0 = expf(sim0 - mx), p1 = expf(sim1 - mx);
        const float inv = 1.f / (p0 + p1);
        const float w0_ = p0 * inv * expf(dl * d0) * m0;
        const float w1_ = p1 * inv * expf(dl * d1) * m1;

        // p_lambda (uses s-side weights; lane 0 lives in half 0)
        {
            float q0 = y[0] - y[1]; q0 *= q0;
            float q1 = y[2] - y[1]; q1 *= q1;
            float q2 = y[3] - y[1]; q2 *= q2;
            float comb = q0 + w0_ * q1 + w1_ * q2;
            #pragma unroll
            for (int m = 1; m <= 16; m <<= 1) comb += __shfl_xor(comb, m);
            if (lane == 0) out[b] = -comb;
        }

        // n_lambda_s (half 0) / n_lambda_t (half 1)
        float* onS = out + nB + (size_t)b * 10;
        float* onT = out + nB + (size_t)nB * 10 + (size_t)b * 10;
        const float Aa = half ? y[1] : y[0];
        const float Ha = half ? y[4] : y[2];
        const float Hb = half ? y[5] : y[3];
        #pragma unroll
        for (int n = 0; n < 10; n++) {
            const float cn = half ? y[6 + n] : y[16 + n];
            float u  = Aa - cn; u  *= u;
            float v0 = Ha - cn; v0 *= v0;
            float v1 = Hb - cn; v1 *= v1;
            float comb = u + w0_ * v0 + w1_ * v1;
            #pragma unroll
            for (int m = 1; m <= 16; m <<= 1) comb += __shfl_xor(comb, m);
            if (lane == n)      onS[n] = -comb;
            if (lane == 32 + n) onT[n] = -comb;
        }
    }
}

extern "C" void kernel_launch(void* const* d_in, const int* in_sizes, int n_in,
                              void* d_out, int out_size, void* d_ws, size_t ws_size,
                              hipStream_t stream) {
    const float* s_fts     = (const float*)d_in[0];
    const float* t_fts     = (const float*)d_in[1];
    const float* s_h_fts   = (const float*)d_in[2];
    const float* t_h_fts   = (const float*)d_in[3];
    const float* s_neg     = (const float*)d_in[4];
    const float* t_neg     = (const float*)d_in[5];
    const float* ev_t      = (const float*)d_in[6];
    const float* s_h_times = (const float*)d_in[7];
    const float* t_h_times = (const float*)d_in[8];
    const float* s_mask    = (const float*)d_in[9];
    const float* t_mask    = (const float*)d_in[10];
    const float* Wg        = (const float*)d_in[11];
    const float* bft       = (const float*)d_in[12];
    const float* av        = (const float*)d_in[13];
    const float* dels      = (const float*)d_in[14];
    const float* delt      = (const float*)d_in[15];

    const int nB = in_sizes[6];           // B = 50000
    const int blocks = (nB + GB - 1) / GB;  // 3125, exact

    mmdne_kernel<<<blocks, 256, 0, stream>>>(
        s_fts, t_fts, s_h_fts, t_h_fts, s_neg, t_neg, ev_t,
        s_h_times, t_h_times, s_mask, t_mask, Wg, bft, av, dels, delt,
        (float*)d_out, nB);
}